// Round 5
// baseline (383.415 us; speedup 1.0000x reference)
//
#include <hip/hip_runtime.h>
#include <hip/hip_bf16.h>

// Problem constants (reference: B=2048, F=512, U=512, G=64, REG_STRENGTH=1.0)
#define B_SZ 2048
#define F_SZ 512
#define U_SZ 512
#define G_SZ 64
#define REG_STRENGTH 1.0f

// Streaming MFMA grouped GEMM, no LDS, no barriers, split-K for TLP.
// Wave tile: 64 rows (4 A-subtiles) x 16 cols x K=128 (blockIdx.z of 4).
// Block = 4 waves covering 64 u-cols. Grid (8 u-strips, 96 chunks, 4 ksplits)
// => 8192 working waves = 8 waves/SIMD at VGPR<=64 — latency hidden by TLP.
#define BM 64
#define NXT (U_SZ / 64)              // 8 blocks in u
#define MAXCH 96                     // worst-case chunk slots
#define KSPLIT 4
#define KLEN (F_SZ / KSPLIT)         // 128 per z-slice

typedef __attribute__((ext_vector_type(8))) short bf16x8;  // 8 bf16 = 4 VGPR
typedef __attribute__((ext_vector_type(4))) float f32x4;

// Workspace int layout
#define WS_WSF      0   // float: weighted (w+b) reg-loss accumulator
#define WS_TICKET   1
#define WS_NCH      2
#define WS_COUNTS   4
#define WS_ROWSTART (4 + G_SZ)
#define WS_ORDER    (4 + 2 * G_SZ)
#define WS_CHUNKS   (4 + 2 * G_SZ + B_SZ)

// f32 pair -> packed bf16 pair (RNE), ~2.5 VALU ops per value pair.
__device__ __forceinline__ unsigned rnepack(float lo, float hi) {
  unsigned a = __float_as_uint(lo), b = __float_as_uint(hi);
  a += 0x7FFFu + ((a >> 16) & 1u);
  b += 0x7FFFu + ((b >> 16) & 1u);
  return __builtin_amdgcn_perm(b, a, 0x07060302);  // {hi16(b),hi16(a)}
}

__device__ __forceinline__ bf16x8 cvt8(float4 p, float4 q) {
  union { unsigned u[4]; bf16x8 v; } r;
  r.u[0] = rnepack(p.x, p.y);
  r.u[1] = rnepack(p.z, p.w);
  r.u[2] = rnepack(q.x, q.y);
  r.u[3] = rnepack(q.z, q.w);
  return r.v;
}

// ---------------------------------------------------------------------------
// Kernel A: histogram gid -> counts, prefix -> rowstart, scatter -> order,
// build BM-row chunk worklist. Zero wsf/ticket.
// ---------------------------------------------------------------------------
__global__ __launch_bounds__(1024) void prep_kernel(
    const int* __restrict__ gid, int* __restrict__ wsi) {
  __shared__ int cnt_s[G_SZ];
  __shared__ int cur_s[G_SZ];
  __shared__ int chk_s[G_SZ];
  const int tid = threadIdx.x;

  if (tid < G_SZ) cnt_s[tid] = 0;
  if (tid == 0) { ((float*)wsi)[WS_WSF] = 0.0f; wsi[WS_TICKET] = 0; }
  __syncthreads();

  for (int b = tid; b < B_SZ; b += 1024) atomicAdd(&cnt_s[gid[b]], 1);
  __syncthreads();

  if (tid == 0) {
    int run = 0, crun = 0;
    for (int g = 0; g < G_SZ; ++g) {
      cur_s[g] = run;
      chk_s[g] = crun;
      run += cnt_s[g];
      crun += (cnt_s[g] + BM - 1) / BM;
    }
    wsi[WS_NCH] = crun;
  }
  __syncthreads();

  if (tid < G_SZ) {
    wsi[WS_COUNTS + tid] = cnt_s[tid];
    wsi[WS_ROWSTART + tid] = cur_s[tid];
    const int nch = (cnt_s[tid] + BM - 1) / BM;
    const int cs = chk_s[tid];
    for (int i = 0; i < nch; ++i)
      wsi[WS_CHUNKS + cs + i] = tid | ((i * BM) << 8);  // g | (r0<<8)
  }
  __syncthreads();  // rowstart snapshot before scatter mutates cur_s

  for (int b = tid; b < B_SZ; b += 1024) {
    int pos = atomicAdd(&cur_s[gid[b]], 1);
    wsi[WS_ORDER + pos] = b;
  }
}

// ---------------------------------------------------------------------------
// Kernel B: barrier-free streaming bf16-MFMA grouped GEMM, split-K.
// block = (u-strip x, chunk slot y, ksplit z); wave w: cols [x*64+16w, +16),
// rows [r0, r0+64), k in [z*128, z*128+128). Partial results atomicAdd into
// the pre-zeroed out; z==0 adds the bias. W reg loss fused on r0==0 chunks
// (k-partitioned across z); b-loss on (x==0, z==0, fq==0). Ticket block
// writes the weighted scalar.
// ---------------------------------------------------------------------------
__global__ __launch_bounds__(256) void gemm_kernel(
    const float* __restrict__ x, const float* __restrict__ w_mu,
    const float* __restrict__ b_mu, const float* __restrict__ w0_mu,
    const float* __restrict__ b0_mu, float* __restrict__ out,
    int* __restrict__ wsi) {
  const int tid = threadIdx.x;
  const int lane = tid & 63;
  const int wave = tid >> 6;
  const int fl = lane & 15;   // A row / B col within subtile
  const int fq = lane >> 4;   // quad: input k-block = fq*8; output row = fq*4+i
  const int slot = blockIdx.y;
  const int nch = wsi[WS_NCH];

  if (slot < nch) {
    const int entry = wsi[WS_CHUNKS + slot];
    const int g = entry & 0xFF;
    const int r0 = entry >> 8;
    const int cnt = wsi[WS_COUNTS + g];
    const int rs = wsi[WS_ROWSTART + g];
    const int ucol = blockIdx.x * 64 + wave * 16 + fl;  // this lane's B col
    const int k0 = blockIdx.z * KLEN;
    const bool do_reg = (r0 == 0);
    float regp = 0.0f;

    // Fragment base pointers (k0 and fq*8 folded in)
    const float* __restrict__ wrow =
        w_mu + ((size_t)g * U_SZ + ucol) * F_SZ + k0 + fq * 8;
    const float* __restrict__ w0row = w0_mu + (size_t)ucol * F_SZ + k0 + fq * 8;
    const float* xrow[4];
#pragma unroll
    for (int mt = 0; mt < 4; ++mt) {
      int r = r0 + mt * 16 + fl;
      if (r >= cnt) r = cnt - 1;  // clamp; padded rows never stored
      xrow[mt] = x + (size_t)wsi[WS_ORDER + rs + r] * F_SZ + k0 + fq * 8;
    }

    f32x4 acc[4] = {{0.f, 0.f, 0.f, 0.f}, {0.f, 0.f, 0.f, 0.f},
                    {0.f, 0.f, 0.f, 0.f}, {0.f, 0.f, 0.f, 0.f}};

#pragma unroll
    for (int kc = 0; kc < KLEN; kc += 32) {
      // B fragment: 8 contiguous f32 of this lane's W row
      const float4 wa = *(const float4*)(wrow + kc);
      const float4 wb = *(const float4*)(wrow + kc + 4);
      if (do_reg) {  // fused W reg loss on exact f32 values (this k-slice)
        const float4 za = *(const float4*)(w0row + kc);
        const float4 zb = *(const float4*)(w0row + kc + 4);
        float d0 = wa.x - za.x, d1 = wa.y - za.y, d2 = wa.z - za.z,
              d3 = wa.w - za.w, d4 = wb.x - zb.x, d5 = wb.y - zb.y,
              d6 = wb.z - zb.z, d7 = wb.w - zb.w;
        regp += d0 * d0 + d1 * d1 + d2 * d2 + d3 * d3 + d4 * d4 + d5 * d5 +
                d6 * d6 + d7 * d7;
      }
      const bf16x8 bfrag = cvt8(wa, wb);
#pragma unroll
      for (int mt = 0; mt < 4; ++mt) {
        const float4 xa = *(const float4*)(xrow[mt] + kc);
        const float4 xb = *(const float4*)(xrow[mt] + kc + 4);
        const bf16x8 afrag = cvt8(xa, xb);
        acc[mt] =
            __builtin_amdgcn_mfma_f32_16x16x32_bf16(afrag, bfrag, acc[mt], 0, 0, 0);
      }
    }

    // Epilogue: accumulate partials into zeroed out; z==0 contributes bias.
    const float bias = (blockIdx.z == 0) ? b_mu[(g << 9) + ucol] : 0.0f;
    if (do_reg && fq == 0 && blockIdx.z == 0) {  // b-loss once per (g,u)
      const float d = b_mu[(g << 9) + ucol] - b0_mu[ucol];
      regp += d * d;
    }
#pragma unroll
    for (int mt = 0; mt < 4; ++mt) {
#pragma unroll
      for (int i = 0; i < 4; ++i) {
        const int r = r0 + mt * 16 + fq * 4 + i;
        if (r < cnt) {
          const int brow = wsi[WS_ORDER + rs + r];
          atomicAdd(&out[(size_t)brow * U_SZ + ucol], acc[mt][i] + bias);
        }
      }
    }

    // Wave-reduce reg partials, weight by count, one atomic per wave.
    if (do_reg) {
#pragma unroll
      for (int off = 32; off > 0; off >>= 1) regp += __shfl_down(regp, off);
      if (lane == 0) atomicAdd((float*)&wsi[WS_WSF], (float)cnt * regp);
    }
  }

  // Ticket: last block overall writes the scalar reg loss.
  __threadfence();
  if (tid == 0) {
    const int total = (int)(gridDim.x * gridDim.y * gridDim.z);
    if (atomicAdd(&wsi[WS_TICKET], 1) == total - 1) {
      float v = atomicAdd((float*)&wsi[WS_WSF], 0.0f);  // coherent read
      out[(size_t)B_SZ * U_SZ] = REG_STRENGTH * v;
    }
  }
}

extern "C" void kernel_launch(void* const* d_in, const int* in_sizes, int n_in,
                              void* d_out, int out_size, void* d_ws, size_t ws_size,
                              hipStream_t stream) {
  const float* x     = (const float*)d_in[0];
  const int*   gid   = (const int*)d_in[1];
  const float* w_mu  = (const float*)d_in[2];
  const float* b_mu  = (const float*)d_in[3];
  const float* w0_mu = (const float*)d_in[4];
  const float* b0_mu = (const float*)d_in[5];
  float* out = (float*)d_out;
  int* wsi = (int*)d_ws;

  // Zero outputs so split-K partials can atomicAdd (d_out is poisoned 0xAA
  // before every timed launch). hipMemsetAsync is graph-capture-safe.
  hipMemsetAsync(out, 0, (size_t)out_size * sizeof(float), stream);

  prep_kernel<<<1, 1024, 0, stream>>>(gid, wsi);
  gemm_kernel<<<dim3(NXT, MAXCH, KSPLIT), 256, 0, stream>>>(
      x, w_mu, b_mu, w0_mu, b0_mu, out, wsi);
}

// Round 6
// 265.601 us; speedup vs baseline: 1.4436x; 1.4436x over previous
//
#include <hip/hip_runtime.h>
#include <hip/hip_bf16.h>

// Problem constants (reference: B=2048, F=512, U=512, G=64, REG_STRENGTH=1.0)
#define B_SZ 2048
#define F_SZ 512
#define U_SZ 512
#define G_SZ 64
#define REG_STRENGTH 1.0f

// Block tile: 64 rows x 32 cols, BK=128 (4 K-iters). 256 threads = 4 waves;
// wave w owns rows [16w,16w+16) x all 32 cols (2 MFMA col-subtiles).
// Grid (16 u-strips, 96 chunk slots) -> ~1024 working blocks = 4 blocks/CU
// = 16 waves/CU = 4 waves/SIMD. W read from HBM exactly once.
#define BN 32
#define BK 128
#define KITERS (F_SZ / BK)   // 4
#define NXT (U_SZ / BN)      // 16
#define MAXCH 96             // worst-case chunk slots (63*1 + 32)
#define XSTR 136             // LDS row stride in bf16 (128 + 8 pad; 272B = 17*16)
#define WSTR 136

typedef __attribute__((ext_vector_type(8))) short bf16x8;  // 8 bf16 = 4 VGPR
typedef __attribute__((ext_vector_type(4))) float f32x4;

// Workspace int layout
#define WS_WSF      0   // float: weighted (w+b) reg-loss accumulator
#define WS_TICKET   1
#define WS_NCH      2
#define WS_COUNTS   4
#define WS_ROWSTART (4 + G_SZ)
#define WS_ORDER    (4 + 2 * G_SZ)
#define WS_CHUNKS   (4 + 2 * G_SZ + B_SZ)

// f32 pair -> packed bf16 pair (RNE)
__device__ __forceinline__ unsigned rnepack(float lo, float hi) {
  unsigned a = __float_as_uint(lo), b = __float_as_uint(hi);
  a += 0x7FFFu + ((a >> 16) & 1u);
  b += 0x7FFFu + ((b >> 16) & 1u);
  return __builtin_amdgcn_perm(b, a, 0x07060302);  // {hi16(b),hi16(a)}
}

__device__ __forceinline__ uint4 pack8(const float4 p, const float4 q) {
  uint4 r;
  r.x = rnepack(p.x, p.y);
  r.y = rnepack(p.z, p.w);
  r.z = rnepack(q.x, q.y);
  r.w = rnepack(q.z, q.w);
  return r;
}

// ---------------------------------------------------------------------------
// Kernel A: histogram gid -> counts, prefix -> rowstart, scatter -> order,
// build 64-row chunk worklist. Zero wsf/ticket.
// ---------------------------------------------------------------------------
__global__ __launch_bounds__(1024) void prep_kernel(
    const int* __restrict__ gid, int* __restrict__ wsi) {
  __shared__ int cnt_s[G_SZ];
  __shared__ int cur_s[G_SZ];
  __shared__ int chk_s[G_SZ];
  const int tid = threadIdx.x;

  if (tid < G_SZ) cnt_s[tid] = 0;
  if (tid == 0) { ((float*)wsi)[WS_WSF] = 0.0f; wsi[WS_TICKET] = 0; }
  __syncthreads();

  for (int b = tid; b < B_SZ; b += 1024) atomicAdd(&cnt_s[gid[b]], 1);
  __syncthreads();

  if (tid == 0) {
    int run = 0, crun = 0;
    for (int g = 0; g < G_SZ; ++g) {
      cur_s[g] = run;
      chk_s[g] = crun;
      run += cnt_s[g];
      crun += (cnt_s[g] + 63) / 64;
    }
    wsi[WS_NCH] = crun;
  }
  __syncthreads();

  if (tid < G_SZ) {
    wsi[WS_COUNTS + tid] = cnt_s[tid];
    wsi[WS_ROWSTART + tid] = cur_s[tid];
    const int nch = (cnt_s[tid] + 63) / 64;
    const int cs = chk_s[tid];
    for (int i = 0; i < nch; ++i)
      wsi[WS_CHUNKS + cs + i] = tid | ((i * 64) << 8);  // g | (r0<<8)
  }
  __syncthreads();  // rowstart snapshot before scatter mutates cur_s

  for (int b = tid; b < B_SZ; b += 1024) {
    int pos = atomicAdd(&cur_s[gid[b]], 1);
    wsi[WS_ORDER + pos] = b;
  }
}

// ---------------------------------------------------------------------------
// Kernel B: LDS-staged bf16-MFMA grouped GEMM, batched-load pipeline.
// Per K-iter each thread batches 12-16 independent float4 loads into regs
// (in flight during the previous iter's compute), converts to bf16, stages
// into padded LDS tiles, MFMAs from LDS. Two barriers per iter (m97 shape).
// Reg loss fused on r0==0 chunks (f32 pre-conversion); strips partition cols
// so each W element and each (g,u) bias is counted exactly once. Plain
// stores (no atomics): row-chunks x col-strips partition out.
// ---------------------------------------------------------------------------
__global__ __launch_bounds__(256, 4) void gemm_kernel(
    const float* __restrict__ x, const float* __restrict__ w_mu,
    const float* __restrict__ b_mu, const float* __restrict__ w0_mu,
    const float* __restrict__ b0_mu, float* __restrict__ out,
    int* __restrict__ wsi) {
  const int tid = threadIdx.x;
  const int lane = tid & 63;
  const int wave = tid >> 6;
  const int fl = lane & 15;   // MFMA: A row / B col / D col
  const int fq = lane >> 4;   // quad: input k-off = fq*8; output row = fq*4+i
  const int slot = blockIdx.y;
  const int nch = wsi[WS_NCH];

  __shared__ __align__(16) unsigned short Xs[64][XSTR];   // 17.0 KB
  __shared__ __align__(16) unsigned short Ws[BN][WSTR];   //  8.5 KB

  if (slot < nch) {
    const int entry = wsi[WS_CHUNKS + slot];
    const int g = entry & 0xFF;
    const int r0 = entry >> 8;
    const int cnt = wsi[WS_COUNTS + g];
    const int rs = wsi[WS_ROWSTART + g];
    const int n0 = blockIdx.x * BN;
    const bool do_reg = (r0 == 0);
    float regp = 0.0f;

    // --- staging maps ---
    // X: thread t covers row trow = t>>2, k-seg xseg = t&3 (32 f32 each)
    const int trow = tid >> 2;
    const int xseg = tid & 3;
    int rr = r0 + trow;
    if (rr >= cnt) rr = cnt - 1;  // clamp; padded rows never stored
    const float* __restrict__ xptr =
        x + (size_t)wsi[WS_ORDER + rs + rr] * F_SZ + xseg * 32;
    // W: thread t covers col wrow = t>>3, k-seg wseg = t&7 (16 f32 each)
    const int wrow = tid >> 3;
    const int wseg = tid & 7;
    const float* __restrict__ wptr =
        w_mu + ((size_t)g * U_SZ + n0 + wrow) * F_SZ + wseg * 16;
    const float* __restrict__ w0ptr =
        w0_mu + (size_t)(n0 + wrow) * F_SZ + wseg * 16;

    f32x4 acc[2] = {{0.f, 0.f, 0.f, 0.f}, {0.f, 0.f, 0.f, 0.f}};

    float4 xr[8], wr[4], zr[4];
    // prologue: batch-load iter 0 (all independent)
#pragma unroll
    for (int j = 0; j < 8; ++j) xr[j] = *(const float4*)(xptr + j * 4);
#pragma unroll
    for (int j = 0; j < 4; ++j) wr[j] = *(const float4*)(wptr + j * 4);
    if (do_reg)
#pragma unroll
      for (int j = 0; j < 4; ++j) zr[j] = *(const float4*)(w0ptr + j * 4);

#pragma unroll
    for (int it = 0; it < KITERS; ++it) {
      __syncthreads();  // previous iter's LDS readers done
      // ---- cvt + stage into LDS ----
#pragma unroll
      for (int q = 0; q < 4; ++q)
        *(uint4*)&Xs[trow][xseg * 32 + q * 8] = pack8(xr[2 * q], xr[2 * q + 1]);
#pragma unroll
      for (int q = 0; q < 2; ++q)
        *(uint4*)&Ws[wrow][wseg * 16 + q * 8] = pack8(wr[2 * q], wr[2 * q + 1]);
      if (do_reg) {  // fused W reg loss on exact f32 values
#pragma unroll
        for (int j = 0; j < 4; ++j) {
          float d0 = wr[j].x - zr[j].x, d1 = wr[j].y - zr[j].y;
          float d2 = wr[j].z - zr[j].z, d3 = wr[j].w - zr[j].w;
          regp += d0 * d0 + d1 * d1 + d2 * d2 + d3 * d3;
        }
      }
      __syncthreads();  // LDS tile visible
      // ---- batch-issue next iter's loads (fly during compute) ----
      if (it + 1 < KITERS) {
        const int kc = (it + 1) * BK;
#pragma unroll
        for (int j = 0; j < 8; ++j) xr[j] = *(const float4*)(xptr + kc + j * 4);
#pragma unroll
        for (int j = 0; j < 4; ++j) wr[j] = *(const float4*)(wptr + kc + j * 4);
        if (do_reg)
#pragma unroll
          for (int j = 0; j < 4; ++j) zr[j] = *(const float4*)(w0ptr + kc + j * 4);
      }
      // ---- compute: 4 k-steps x 2 col-subtiles of 16x16x32 bf16 MFMA ----
#pragma unroll
      for (int ks = 0; ks < 4; ++ks) {
        const bf16x8 a = *(const bf16x8*)&Xs[wave * 16 + fl][ks * 32 + fq * 8];
#pragma unroll
        for (int s = 0; s < 2; ++s) {
          const bf16x8 b = *(const bf16x8*)&Ws[s * 16 + fl][ks * 32 + fq * 8];
          acc[s] = __builtin_amdgcn_mfma_f32_16x16x32_bf16(a, b, acc[s], 0, 0, 0);
        }
      }
    }

    // ---- epilogue: bias + b-loss + scatter stores ----
#pragma unroll
    for (int s = 0; s < 2; ++s) {
      const int gcol = n0 + s * 16 + fl;
      const float bias = b_mu[(g << 9) + gcol];
      if (do_reg && wave == 0 && fq == 0) {  // each (g,u) exactly once
        const float d = bias - b0_mu[gcol];
        regp += d * d;
      }
#pragma unroll
      for (int i = 0; i < 4; ++i) {
        const int r = r0 + wave * 16 + fq * 4 + i;
        if (r < cnt) {
          const int brow = wsi[WS_ORDER + rs + r];
          out[(size_t)brow * U_SZ + gcol] = acc[s][i] + bias;
        }
      }
    }

    // ---- wave-reduce reg partials, weight by count, one atomic per wave ----
    if (do_reg) {
#pragma unroll
      for (int off = 32; off > 0; off >>= 1) regp += __shfl_down(regp, off);
      if (lane == 0) atomicAdd((float*)&wsi[WS_WSF], (float)cnt * regp);
    }
  }

  // Ticket: last block overall writes the scalar reg loss.
  __threadfence();
  if (tid == 0) {
    const int total = (int)(gridDim.x * gridDim.y);
    if (atomicAdd(&wsi[WS_TICKET], 1) == total - 1) {
      float v = atomicAdd((float*)&wsi[WS_WSF], 0.0f);  // coherent read
      out[(size_t)B_SZ * U_SZ] = REG_STRENGTH * v;
    }
  }
}

extern "C" void kernel_launch(void* const* d_in, const int* in_sizes, int n_in,
                              void* d_out, int out_size, void* d_ws, size_t ws_size,
                              hipStream_t stream) {
  const float* x     = (const float*)d_in[0];
  const int*   gid   = (const int*)d_in[1];
  const float* w_mu  = (const float*)d_in[2];
  const float* b_mu  = (const float*)d_in[3];
  const float* w0_mu = (const float*)d_in[4];
  const float* b0_mu = (const float*)d_in[5];
  float* out = (float*)d_out;
  int* wsi = (int*)d_ws;

  prep_kernel<<<1, 1024, 0, stream>>>(gid, wsi);
  gemm_kernel<<<dim3(NXT, MAXCH), 256, 0, stream>>>(
      x, w_mu, b_mu, w0_mu, b0_mu, out, wsi);
}

// Round 7
// 235.318 us; speedup vs baseline: 1.6293x; 1.1287x over previous
//
#include <hip/hip_runtime.h>
#include <hip/hip_bf16.h>

// Problem constants (reference: B=2048, F=512, U=512, G=64, REG_STRENGTH=1.0)
#define B_SZ 2048
#define F_SZ 512
#define U_SZ 512
#define G_SZ 64
#define REG_STRENGTH 1.0f

// f32 FMA grouped GEMM (R2 structure, fixed wave supply).
// Block: 128 threads (2 waves), tile 32 rows x 32 cols, BK=32, per-thread
// 2x4 register tile (256 FMAs per K-iter = the latency hider).
// Grid (16 u-strips, 128 chunk slots): ~1536 working blocks = ~3 waves/SIMD.
#define BM 32
#define BN 32
#define BK 32
#define NXT (U_SZ / BN)            // 16
#define MAXCH (B_SZ / BM + G_SZ)   // 128 worst-case chunk slots
#define THREADS 128

// Workspace int layout
#define WS_WSF      0   // float: weighted (w+b) reg-loss accumulator
#define WS_TICKET   1
#define WS_NCH      2
#define WS_COUNTS   4
#define WS_ROWSTART (4 + G_SZ)
#define WS_ORDER    (4 + 2 * G_SZ)
#define WS_CHUNKS   (4 + 2 * G_SZ + B_SZ)

// ---------------------------------------------------------------------------
// Kernel A: histogram gid -> counts, prefix -> rowstart, scatter -> order,
// build 32-row chunk worklist. Zero wsf/ticket.
// ---------------------------------------------------------------------------
__global__ __launch_bounds__(1024) void prep_kernel(
    const int* __restrict__ gid, int* __restrict__ wsi) {
  __shared__ int cnt_s[G_SZ];
  __shared__ int cur_s[G_SZ];
  __shared__ int chk_s[G_SZ];
  const int tid = threadIdx.x;

  if (tid < G_SZ) cnt_s[tid] = 0;
  if (tid == 0) { ((float*)wsi)[WS_WSF] = 0.0f; wsi[WS_TICKET] = 0; }
  __syncthreads();

  for (int b = tid; b < B_SZ; b += 1024) atomicAdd(&cnt_s[gid[b]], 1);
  __syncthreads();

  if (tid == 0) {
    int run = 0, crun = 0;
    for (int g = 0; g < G_SZ; ++g) {
      cur_s[g] = run;
      chk_s[g] = crun;
      run += cnt_s[g];
      crun += (cnt_s[g] + BM - 1) / BM;
    }
    wsi[WS_NCH] = crun;
  }
  __syncthreads();

  if (tid < G_SZ) {
    wsi[WS_COUNTS + tid] = cnt_s[tid];
    wsi[WS_ROWSTART + tid] = cur_s[tid];
    const int nch = (cnt_s[tid] + BM - 1) / BM;
    const int cs = chk_s[tid];
    for (int i = 0; i < nch; ++i)
      wsi[WS_CHUNKS + cs + i] = tid | ((i * BM) << 8);  // g | (r0<<8)
  }
  __syncthreads();  // rowstart snapshot before scatter mutates cur_s

  for (int b = tid; b < B_SZ; b += 1024) {
    int pos = atomicAdd(&cur_s[gid[b]], 1);
    wsi[WS_ORDER + pos] = b;
  }
}

// ---------------------------------------------------------------------------
// Kernel B: f32 grouped GEMM, register-double-buffered LDS staging (the
// measured-best R2 structure). block = (u-strip x, chunk slot y).
// Reg loss fused: W-loss on r0==0 chunks (cols partitioned by strip => each
// W element once); b-loss by tm==0 threads of (r0==0) blocks. Plain stores.
// ---------------------------------------------------------------------------
__global__ __launch_bounds__(THREADS) void gemm_kernel(
    const float* __restrict__ x, const float* __restrict__ w_mu,
    const float* __restrict__ b_mu, const float* __restrict__ w0_mu,
    const float* __restrict__ b0_mu, float* __restrict__ out,
    int* __restrict__ wsi) {
  const int tid = threadIdx.x;
  const int lane = tid & 63;
  const int slot = blockIdx.y;
  const int nch = wsi[WS_NCH];

  __shared__ __align__(16) float Xs[BK][BM + 4];  // 4.5 KB
  __shared__ __align__(16) float Ws[BK][BN + 4];  // 4.5 KB
  __shared__ float red[THREADS];

  if (slot < nch) {
    const int entry = wsi[WS_CHUNKS + slot];
    const int g = entry & 0xFF;
    const int r0 = entry >> 8;
    const int cnt = wsi[WS_COUNTS + g];
    const int rs = wsi[WS_ROWSTART + g];
    const int n0 = blockIdx.x * BN;
    const bool do_reg = (r0 == 0);
    float regp = 0.0f;

    // staging map: f4 idx = tid + 128*j (j=0,1) -> row idx>>3, k-quad idx&7
    const int sr0 = tid >> 3;          // 0..15  (j=0 rows/cols)
    const int skq = tid & 7;           // 0..7
    const int kb = skq * 4;
    // compute map: 2 rows x 4 cols per thread
    const int tm = tid >> 3;           // 0..15 -> rows {2tm, 2tm+1}
    const int tn = tid & 7;            // 0..7  -> cols tn*4..+3

    int rA = r0 + sr0;      if (rA >= cnt) rA = cnt - 1;  // clamp (not stored)
    int rB = r0 + sr0 + 16; if (rB >= cnt) rB = cnt - 1;
    const float* __restrict__ xrowA = x + (size_t)wsi[WS_ORDER + rs + rA] * F_SZ;
    const float* __restrict__ xrowB = x + (size_t)wsi[WS_ORDER + rs + rB] * F_SZ;
    const float* __restrict__ wrowA =
        w_mu + ((size_t)g * U_SZ + n0 + sr0) * F_SZ;
    const float* __restrict__ wrowB =
        w_mu + ((size_t)g * U_SZ + n0 + sr0 + 16) * F_SZ;
    const float* __restrict__ w0rowA = w0_mu + (size_t)(n0 + sr0) * F_SZ;
    const float* __restrict__ w0rowB = w0_mu + (size_t)(n0 + sr0 + 16) * F_SZ;

    float acc[2][4] = {};

    // prologue: prefetch chunk 0
    float4 xpA = *(const float4*)(xrowA + kb);
    float4 xpB = *(const float4*)(xrowB + kb);
    float4 wpA = *(const float4*)(wrowA + kb);
    float4 wpB = *(const float4*)(wrowB + kb);

    for (int kc = 0; kc < F_SZ; kc += BK) {
      __syncthreads();  // previous iter's LDS readers done
      // ---- store prefetched registers into LDS (transposed [k][m/u]) ----
      Xs[kb + 0][sr0] = xpA.x; Xs[kb + 1][sr0] = xpA.y;
      Xs[kb + 2][sr0] = xpA.z; Xs[kb + 3][sr0] = xpA.w;
      Xs[kb + 0][sr0 + 16] = xpB.x; Xs[kb + 1][sr0 + 16] = xpB.y;
      Xs[kb + 2][sr0 + 16] = xpB.z; Xs[kb + 3][sr0 + 16] = xpB.w;
      Ws[kb + 0][sr0] = wpA.x; Ws[kb + 1][sr0] = wpA.y;
      Ws[kb + 2][sr0] = wpA.z; Ws[kb + 3][sr0] = wpA.w;
      Ws[kb + 0][sr0 + 16] = wpB.x; Ws[kb + 1][sr0 + 16] = wpB.y;
      Ws[kb + 2][sr0 + 16] = wpB.z; Ws[kb + 3][sr0 + 16] = wpB.w;
      // ---- fused W reg loss on exact f32 values (w0 inline, L2/L3-warm) ----
      if (do_reg) {
        const float4 zA = *(const float4*)(w0rowA + kc + kb);
        const float4 zB = *(const float4*)(w0rowB + kc + kb);
        float a0 = wpA.x - zA.x, a1 = wpA.y - zA.y, a2 = wpA.z - zA.z,
              a3 = wpA.w - zA.w;
        float b0 = wpB.x - zB.x, b1 = wpB.y - zB.y, b2 = wpB.z - zB.z,
              b3 = wpB.w - zB.w;
        regp += a0 * a0 + a1 * a1 + a2 * a2 + a3 * a3 + b0 * b0 + b1 * b1 +
                b2 * b2 + b3 * b3;
      }
      __syncthreads();  // tile visible
      // ---- issue next iter's loads; they fly during the FMA burst ----
      if (kc + BK < F_SZ) {
        const int ko = kc + BK + kb;
        xpA = *(const float4*)(xrowA + ko);
        xpB = *(const float4*)(xrowB + ko);
        wpA = *(const float4*)(wrowA + ko);
        wpB = *(const float4*)(wrowB + ko);
      }
      // ---- compute: 2x4 tile over BK (256 FMAs/thread) ----
#pragma unroll
      for (int kk = 0; kk < BK; ++kk) {
        const float a0 = Xs[kk][tm * 2];
        const float a1 = Xs[kk][tm * 2 + 1];
        const float4 bv = *(const float4*)&Ws[kk][tn * 4];
        acc[0][0] += a0 * bv.x; acc[0][1] += a0 * bv.y;
        acc[0][2] += a0 * bv.z; acc[0][3] += a0 * bv.w;
        acc[1][0] += a1 * bv.x; acc[1][1] += a1 * bv.y;
        acc[1][2] += a1 * bv.z; acc[1][3] += a1 * bv.w;
      }
    }

    // ---- epilogue: bias + b-loss + partitioned stores ----
    const float4 bias = *(const float4*)(b_mu + (g << 9) + n0 + tn * 4);
    if (do_reg && tm == 0) {  // each (g, col) counted once per strip
      const float4 z = *(const float4*)(b0_mu + n0 + tn * 4);
      float d0 = bias.x - z.x, d1 = bias.y - z.y;
      float d2 = bias.z - z.z, d3 = bias.w - z.w;
      regp += d0 * d0 + d1 * d1 + d2 * d2 + d3 * d3;
    }
#pragma unroll
    for (int i = 0; i < 2; ++i) {
      const int r = r0 + tm * 2 + i;
      if (r < cnt) {
        const int brow = wsi[WS_ORDER + rs + r];
        float4 o;
        o.x = acc[i][0] + bias.x;
        o.y = acc[i][1] + bias.y;
        o.z = acc[i][2] + bias.z;
        o.w = acc[i][3] + bias.w;
        *(float4*)(out + (size_t)brow * U_SZ + n0 + tn * 4) = o;
      }
    }

    // ---- block-reduce reg partials, weight by cnt, one atomic ----
    if (do_reg) {
#pragma unroll
      for (int off = 32; off > 0; off >>= 1) regp += __shfl_down(regp, off);
      if (lane == 0) red[tid >> 6] = regp;
      __syncthreads();
      if (tid == 0)
        atomicAdd((float*)&wsi[WS_WSF], (float)cnt * (red[0] + red[1]));
    }
  }

  // Ticket: last block overall writes the scalar reg loss.
  __threadfence();
  if (tid == 0) {
    const int total = (int)(gridDim.x * gridDim.y);
    if (atomicAdd(&wsi[WS_TICKET], 1) == total - 1) {
      float v = atomicAdd((float*)&wsi[WS_WSF], 0.0f);  // coherent read
      out[(size_t)B_SZ * U_SZ] = REG_STRENGTH * v;
    }
  }
}

extern "C" void kernel_launch(void* const* d_in, const int* in_sizes, int n_in,
                              void* d_out, int out_size, void* d_ws, size_t ws_size,
                              hipStream_t stream) {
  const float* x     = (const float*)d_in[0];
  const int*   gid   = (const int*)d_in[1];
  const float* w_mu  = (const float*)d_in[2];
  const float* b_mu  = (const float*)d_in[3];
  const float* w0_mu = (const float*)d_in[4];
  const float* b0_mu = (const float*)d_in[5];
  float* out = (float*)d_out;
  int* wsi = (int*)d_ws;

  prep_kernel<<<1, 1024, 0, stream>>>(gid, wsi);
  gemm_kernel<<<dim3(NXT, MAXCH), THREADS, 0, stream>>>(
      x, w_mu, b_mu, w0_mu, b0_mu, out, wsi);
}